// Round 7
// baseline (6964.528 us; speedup 1.0000x reference)
//
#include <hip/hip_runtime.h>
#include <cstdint>
#include <cstddef>

// Problem constants (fixed by the reference).
#define B_   2048
#define T_   100
#define U_   512
#define NG_  2048   // 4*U
#define C_   10

// NOTE (r1): hipLaunchCooperativeKernel fails under harness graph capture.
// NOTE (r2/r5): VMEM loads feeding MFMA in-iteration expose L2/L3 latency.
// NOTE (r3): deeper intra-block pipelines neutral at 128^2.
// NOTE (r4/r6): smaller tiles / BK=128 raise traffic or conflicts -> worse.
//   r6's 16-slot rotation (256B row stride) bank-conflicts; only the 8-slot
//   rotation at 128B row stride is conflict-free (verified r0).
// MODEL (r6): ~320MB/phase panel traffic at ~9.5TB/s L2/L3 aggregate is the
// binding term; A-streams thrash the 1.25MB/XCD B slice out of L2 (FETCH 46MB
// > 30MB working set). Lever: cut redundancy with bigger tiles.
// This round: 256x256 tiles (8 waves, 512 thr), 16x->8x redundancy on BOTH
// operands (320->160MB/phase), per-CU iters 40->10. Inner loop = verified r0
// machinery (BK=64, 8-slot rotation, stage->sync->compute->sync).

typedef __attribute__((ext_vector_type(8))) short   short8;
typedef __attribute__((ext_vector_type(4))) float   floatx4;
typedef unsigned short ushort_t;

__device__ inline ushort_t f2bf(float f){
  unsigned u = __float_as_uint(f);
  unsigned r = (u + 0x7FFFu + ((u >> 16) & 1u)) >> 16;   // RNE
  return (ushort_t)r;
}
__device__ inline float bf2f(ushort_t b){ return __uint_as_float(((unsigned)b) << 16); }

__device__ inline float sigm(float x){ return 1.0f / (1.0f + __expf(-x)); }
__device__ inline float tanh_fast(float x){
  float a = fabsf(x);
  float e = __expf(-2.0f * a);          // no overflow: e in (0,1]
  float r = (1.0f - e) / (1.0f + e);
  return copysignf(r, x);
}

// Column permutation for 256-col tiles: permuted col p -> original gate-major
// col. Tile Tt (256 cols) owns u in [Tt*64, Tt*64+64); within tile: four
// 64-col groups (one per wave_n), each = 4 gates x 16 u's, gate-major in
// 16-col subgroups. u = Tt*64 + wave_n*16 + uu.
__device__ inline int orig_col(int p){
  int Tt   = p >> 8;
  int loc  = p & 255;
  int wn   = loc >> 6;
  int loc2 = loc & 63;
  int gate = loc2 >> 4;
  int uu   = loc2 & 15;
  return gate * U_ + Tt * 64 + wn * 16 + uu;
}

#define AS1(p) ((const __attribute__((address_space(1))) void*)(p))
#define AS3(p) ((__attribute__((address_space(3))) void*)(p))

// ---------------------------------------------------------------------------
// One-time weight repack: fp32 -> bf16, B^T (n-major) layout with the
// 256-tile gate-interleaved column permutation. Also permuted biases (fp32)
// and W0 row.
// ---------------------------------------------------------------------------
__global__ void convert_weights(
    const float* __restrict__ W0, const float* __restrict__ U0, const float* __restrict__ b0,
    const float* __restrict__ W1, const float* __restrict__ U1, const float* __restrict__ b1,
    const float* __restrict__ W2, const float* __restrict__ U2, const float* __restrict__ b2,
    ushort_t* __restrict__ Bt0, ushort_t* __restrict__ Bt1, ushort_t* __restrict__ Bt2,
    float* __restrict__ W0p, float* __restrict__ biasp)
{
  const int N0 = NG_ * 512;     // Bt0 elements
  const int N1 = NG_ * 1024;    // Bt1/Bt2 elements
  const int total = N0 + 2 * N1 + NG_ + 3 * NG_;
  int idx = blockIdx.x * 256 + threadIdx.x;
  if (idx >= total) return;

  if (idx < N0){
    int p = idx >> 9, k = idx & 511;
    Bt0[idx] = f2bf(U0[(size_t)k * NG_ + orig_col(p)]);
  } else if (idx < N0 + N1){
    int j = idx - N0; int p = j >> 10, k = j & 1023;
    int oc = orig_col(p);
    float v = (k < 512) ? W1[(size_t)k * NG_ + oc] : U1[(size_t)(k - 512) * NG_ + oc];
    Bt1[j] = f2bf(v);
  } else if (idx < N0 + 2 * N1){
    int j = idx - N0 - N1; int p = j >> 10, k = j & 1023;
    int oc = orig_col(p);
    float v = (k < 512) ? W2[(size_t)k * NG_ + oc] : U2[(size_t)(k - 512) * NG_ + oc];
    Bt2[j] = f2bf(v);
  } else if (idx < N0 + 2 * N1 + NG_){
    int p = idx - N0 - 2 * N1;
    W0p[p] = W0[orig_col(p)];
  } else {
    int j = idx - N0 - 2 * N1 - NG_;
    int l = j >> 11, p = j & 2047;
    const float* bs = (l == 0) ? b0 : (l == 1) ? b1 : b2;
    biasp[j] = bs[orig_col(p)];
  }
}

// ---------------------------------------------------------------------------
// One fused GEMM (bf16 MFMA) + LSTM-cell task for a (layer, timestep),
// 256x256 tile at (mt, nt). BK=64 K-loop: per iter stage 256x64 A and 256x64
// B tiles via global_load_lds(16B) with the verified 8-slot rotation (row
// stride 128B; slot (r,j) holds global chunk (j+r)&7; readback (q-R)&7 ->
// conflict-free). 512 threads = 2x4 waves; each wave owns 128x64 output =
// 8x4 frags of 16x16x32, 2 k-steps/iter (64 MFMA/iter/wave).
// ---------------------------------------------------------------------------
template<int LAYER>
__device__ __forceinline__ void do_task(
    const ushort_t* __restrict__ A0,   // phase-0 A (h_below / h_prev for L0)
    const ushort_t* __restrict__ A1,   // phase-1 A (h_prev), LAYER>0
    const ushort_t* __restrict__ Bt,   // (2048 x K) bf16, n-major permuted
    const float* __restrict__ biasp,   // permuted bias for this layer (2048)
    const float* __restrict__ W0p,     // permuted W0 row (L0 only)
    const float* __restrict__ x,       // (B,T) fp32 (L0 only)
    const int* __restrict__ mask,      // (B,T) int32
    float* __restrict__ cbuf,          // (B,U) fp32, in/out
    const ushort_t* __restrict__ hprev,// this layer's previous h (mask carry)
    ushort_t* __restrict__ hout,       // (B,U) bf16 out
    int t, int mt, int nt,
    ushort_t* tA, ushort_t* tB)        // 256x64 each (32 KB each)
{
  constexpr int NPHASE = (LAYER == 0) ? 1 : 2;
  constexpr bool IS_L0 = (LAYER == 0);
  constexpr int K = NPHASE * 512;

  const int tid  = threadIdx.x;
  const int wv   = tid >> 6;      // 0..7
  const int lane = tid & 63;
  const int qd   = lane >> 4;     // quad 0..3
  const int l16  = lane & 15;
  const int wave_m = wv >> 2;     // 0..1 (128 rows each)
  const int wave_n = wv & 3;      // 0..3 (64 cols each)
  const int m0 = mt * 256, n0 = nt * 256;

  // Staging identity: 2048 16B-chunks per 256x64 tile, 4 per thread per
  // matrix. chunk i = cc*512 + tid: row r = i>>3, slot j = i&7, source
  // chunk (j+r)&7 (verified conflict-free rotation, 128B row stride).
  int srow[4], scol[4];
  #pragma unroll
  for (int cc = 0; cc < 4; ++cc){
    int i = cc * 512 + tid;
    srow[cc] = i >> 3;
    scol[cc] = ((i & 7) + (i >> 3)) & 7;
  }

  // Per-lane LDS read offsets (elements) for frag (ks, w): row R, chunk
  // q = ks*4+qd lives at slot (q - R) & 7. Loop-invariant.
  int aoff[2][8], boff[2][4];
  #pragma unroll
  for (int ks = 0; ks < 2; ++ks){
    #pragma unroll
    for (int w = 0; w < 8; ++w){
      int Ra = wave_m * 128 + w * 16 + l16;
      int q  = ks * 4 + qd;
      aoff[ks][w] = Ra * 64 + ((q - Ra) & 7) * 8;
    }
    #pragma unroll
    for (int w = 0; w < 4; ++w){
      int Rb = wave_n * 64 + w * 16 + l16;
      int q  = ks * 4 + qd;
      boff[ks][w] = Rb * 64 + ((q - Rb) & 7) * 8;
    }
  }

  floatx4 acc[8][4];
  #pragma unroll
  for (int i = 0; i < 8; ++i)
    #pragma unroll
    for (int j = 0; j < 4; ++j) acc[i][j] = (floatx4){0.f, 0.f, 0.f, 0.f};

  #pragma unroll
  for (int ph = 0; ph < NPHASE; ++ph){
    const ushort_t* A = (NPHASE == 2 && ph == 1) ? A1 : A0;
    for (int k0 = 0; k0 < 512; k0 += 64){
      #pragma unroll
      for (int cc = 0; cc < 4; ++cc){
        int ibase = cc * 512 + wv * 64;   // wave-uniform; HW adds lane*16B
        const ushort_t* ga = A + (size_t)(m0 + srow[cc]) * U_ + k0 + scol[cc] * 8;
        __builtin_amdgcn_global_load_lds(AS1(ga), AS3(&tA[ibase * 8]), 16, 0, 0);
        const ushort_t* gb = Bt + (size_t)(n0 + srow[cc]) * K + ph * 512 + k0 + scol[cc] * 8;
        __builtin_amdgcn_global_load_lds(AS1(gb), AS3(&tB[ibase * 8]), 16, 0, 0);
      }
      __syncthreads();

      #pragma unroll
      for (int ks = 0; ks < 2; ++ks){
        short8 af[8], bfr[4];
        #pragma unroll
        for (int w = 0; w < 8; ++w)
          af[w] = *(const short8*)&tA[aoff[ks][w]];
        #pragma unroll
        for (int w = 0; w < 4; ++w)
          bfr[w] = *(const short8*)&tB[boff[ks][w]];
        #pragma unroll
        for (int wm = 0; wm < 8; ++wm)
          #pragma unroll
          for (int wn = 0; wn < 4; ++wn)
            acc[wm][wn] = __builtin_amdgcn_mfma_f32_16x16x32_bf16(af[wm], bfr[wn], acc[wm][wn], 0, 0, 0);
      }
      __syncthreads();
    }
  }

  // ---- epilogue: LSTM cell, fully in-register per lane ----
  const int u  = nt * 64 + wave_n * 16 + l16;
  const int pb = nt * 256 + wave_n * 64 + l16;
  const float bi = biasp[pb], bf_ = biasp[pb + 16], bg = biasp[pb + 32], bo = biasp[pb + 48];
  float wi = 0.f, wf = 0.f, wg = 0.f, wo = 0.f;
  if (IS_L0){ wi = W0p[pb]; wf = W0p[pb + 16]; wg = W0p[pb + 32]; wo = W0p[pb + 48]; }

  #pragma unroll
  for (int wm = 0; wm < 8; ++wm){
    #pragma unroll
    for (int reg = 0; reg < 4; ++reg){
      int b = m0 + wave_m * 128 + wm * 16 + qd * 4 + reg;
      float zi = acc[wm][0][reg] + bi;
      float zf = acc[wm][1][reg] + bf_;
      float zg = acc[wm][2][reg] + bg;
      float zo = acc[wm][3][reg] + bo;
      if (IS_L0){
        float xv = x[(size_t)b * T_ + t];
        zi += xv * wi; zf += xv * wf; zg += xv * wg; zo += xv * wo;
      }
      int mk = mask[(size_t)b * T_ + t];
      size_t su = (size_t)b * U_ + u;
      float c_old = cbuf[su];
      float i_ = sigm(zi), f_ = sigm(zf), g_ = tanh_fast(zg), o_ = sigm(zo);
      float c_new = f_ * c_old + i_ * g_;
      float h_new = o_ * tanh_fast(c_new);
      ushort_t hb = mk ? f2bf(h_new) : hprev[su];
      cbuf[su] = mk ? c_new : c_old;
      hout[su] = hb;
    }
  }
}

// ---------------------------------------------------------------------------
// One wavefront phase: L0(t=s), L1(t=s-1), L2(t=s-2) are independent ->
// 192 blocks (3 tasks x 64 tiles of 256x256), 512 threads each. lin%8 ==
// nt%8 under round-robin XCD dispatch -> per-XCD B slice (1.25MB) stays
// L2-resident; panel redundancy 8x (vs 16x at 128^2).
// ---------------------------------------------------------------------------
__global__ __launch_bounds__(512, 2) void lstm_phase(
    const ushort_t* __restrict__ Bt0, const ushort_t* __restrict__ Bt1,
    const ushort_t* __restrict__ Bt2, const float* __restrict__ biasp,
    const float* __restrict__ W0p, const float* __restrict__ x,
    const int* __restrict__ mask,
    ushort_t* h00, ushort_t* h01, ushort_t* h10, ushort_t* h11,
    ushort_t* h20, ushort_t* h21,
    float* c0, float* c1, float* c2,
    int s)
{
  __shared__ __align__(16) ushort_t tA[256 * 64];   // 32 KB
  __shared__ __align__(16) ushort_t tB[256 * 64];   // 32 KB

  const int lin  = blockIdx.x;
  const int task = lin >> 6;        // 0..2
  const int tile = lin & 63;        // 0..63
  const int mt = tile >> 3, nt = tile & 7;

  ushort_t* h0[2] = {h00, h01};
  ushort_t* h1[2] = {h10, h11};
  ushort_t* h2[2] = {h20, h21};

  if (task == 0){
    if (s >= 100) return;
    int t = s, p = t & 1;
    do_task<0>(h0[p], nullptr, Bt0, biasp, W0p, x, mask,
               c0, h0[p], h0[p ^ 1], t, mt, nt, tA, tB);
  } else if (task == 1){
    if (s < 1 || s > 100) return;
    int t = s - 1, p = t & 1;
    do_task<1>(h0[p ^ 1], h1[p], Bt1, biasp + NG_, nullptr, x, mask,
               c1, h1[p], h1[p ^ 1], t, mt, nt, tA, tB);
  } else {
    if (s < 2) return;
    int t = s - 2, p = t & 1;
    do_task<2>(h1[p ^ 1], h2[p], Bt2, biasp + 2 * NG_, nullptr, x, mask,
               c2, h2[p], h2[p ^ 1], t, mt, nt, tA, tB);
  }
}

// ---------------------------------------------------------------------------
// Head: logits = h2 @ Wd + bd, softmax. One wave per batch row.
// ---------------------------------------------------------------------------
__global__ __launch_bounds__(256) void head_softmax(
    const ushort_t* __restrict__ h2, const float* __restrict__ Wd,
    const float* __restrict__ bd, float* __restrict__ out)
{
  int wv = threadIdx.x >> 6, lane = threadIdx.x & 63;
  int row = blockIdx.x * 4 + wv;
  const ushort_t* hr = h2 + (size_t)row * U_;

  float acc[C_];
  #pragma unroll
  for (int c = 0; c < C_; ++c) acc[c] = 0.f;

  short8 hv = *(const short8*)&hr[lane * 8];
  #pragma unroll
  for (int j = 0; j < 8; ++j){
    float hf = bf2f((ushort_t)hv[j]);
    int k = lane * 8 + j;
    #pragma unroll
    for (int c = 0; c < C_; ++c) acc[c] += hf * Wd[k * C_ + c];
  }
  #pragma unroll
  for (int c = 0; c < C_; ++c){
    float v = acc[c];
    #pragma unroll
    for (int off = 32; off > 0; off >>= 1) v += __shfl_xor(v, off);
    acc[c] = v + bd[c];
  }
  float mx = acc[0];
  #pragma unroll
  for (int c = 1; c < C_; ++c) mx = fmaxf(mx, acc[c]);
  float e[C_]; float s = 0.f;
  #pragma unroll
  for (int c = 0; c < C_; ++c){ e[c] = __expf(acc[c] - mx); s += e[c]; }
  float inv = 1.0f / s;
  if (lane == 0){
    #pragma unroll
    for (int c = 0; c < C_; ++c) out[(size_t)row * C_ + c] = e[c] * inv;
  }
}

// ---------------------------------------------------------------------------
extern "C" void kernel_launch(void* const* d_in, const int* in_sizes, int n_in,
                              void* d_out, int out_size, void* d_ws, size_t ws_size,
                              hipStream_t stream)
{
  const float* x  = (const float*)d_in[0];
  const int*  mask= (const int*)  d_in[1];
  const float* W0 = (const float*)d_in[2];
  const float* U0 = (const float*)d_in[3];
  const float* b0 = (const float*)d_in[4];
  const float* W1 = (const float*)d_in[5];
  const float* U1 = (const float*)d_in[6];
  const float* b1 = (const float*)d_in[7];
  const float* W2 = (const float*)d_in[8];
  const float* U2 = (const float*)d_in[9];
  const float* b2 = (const float*)d_in[10];
  const float* Wd = (const float*)d_in[11];
  const float* bd = (const float*)d_in[12];
  float* out = (float*)d_out;

  char* ws = (char*)d_ws;
  size_t off = 0;
  auto alloc = [&](size_t sz) -> char* {
    char* p = ws + off; off = (off + sz + 255) & ~(size_t)255; return p;
  };
  ushort_t* Bt0  = (ushort_t*)alloc((size_t)NG_ * 512 * 2);
  ushort_t* Bt1  = (ushort_t*)alloc((size_t)NG_ * 1024 * 2);
  ushort_t* Bt2  = (ushort_t*)alloc((size_t)NG_ * 1024 * 2);
  float*    W0p  = (float*)alloc((size_t)NG_ * 4);
  float*    biasp= (float*)alloc((size_t)3 * NG_ * 4);

  // State: h[3][2] (bf16) + c[3] (fp32), one contiguous memset region.
  const size_t hsz = (size_t)B_ * U_ * 2;
  const size_t csz = (size_t)B_ * U_ * 4;
  char* state = alloc(6 * hsz + 3 * csz);
  ushort_t* hb[3][2]; float* cb[3];
  {
    char* pp = state;
    for (int l = 0; l < 3; ++l)
      for (int par = 0; par < 2; ++par){ hb[l][par] = (ushort_t*)pp; pp += hsz; }
    for (int l = 0; l < 3; ++l){ cb[l] = (float*)pp; pp += csz; }
  }

  hipMemsetAsync(state, 0, 6 * hsz + 3 * csz, stream);

  const int total = NG_ * 512 + 2 * NG_ * 1024 + NG_ + 3 * NG_;
  convert_weights<<<(total + 255) / 256, 256, 0, stream>>>(
      W0, U0, b0, W1, U1, b1, W2, U2, b2, Bt0, Bt1, Bt2, W0p, biasp);

  for (int s = 0; s < 102; ++s){
    lstm_phase<<<192, 512, 0, stream>>>(
        Bt0, Bt1, Bt2, biasp, W0p, x, mask,
        hb[0][0], hb[0][1], hb[1][0], hb[1][1], hb[2][0], hb[2][1],
        cb[0], cb[1], cb[2], s);
  }

  // T=100: layer-2 final h (t=99) lands in parity-0 buffer.
  head_softmax<<<B_ / 4, 256, 0, stream>>>(hb[2][0], Wd, bd, out);
}

// Round 8
// 3725.160 us; speedup vs baseline: 1.8696x; 1.8696x over previous
//
#include <hip/hip_runtime.h>
#include <cstdint>
#include <cstddef>

// Problem constants (fixed by the reference).
#define B_   2048
#define T_   100
#define U_   512
#define NG_  2048   // 4*U
#define C_   10

// SESSION LEDGER:
// r0 BASELINE 3425us (33.6us/phase): 128x128, BK=64, A+B LDS rotation,
//    2 barriers/iter, 768 blocks. Best so far.
// r1 cooperative launch: FAILS under harness graph capture.
// r2 A-direct-from-global: 44.5us — h L3 latency exposed on MFMA path.
// r3 BK=32 counted-vmcnt triple-buffer: 43.8us — pipelining not the lever.
// r4 64x128 tiles: 70us — 2x iters, occupancy red herring.
// r5 B-direct frags consumed same-iter + 1 barrier: 49.6us — latency exposed.
// r6 BK=128 16-slot rotation: 50.6us + 2.6M bank conflicts (only the 8-slot
//    rotation at 128B row stride is conflict-free).
// r7 256x256: 84.9us — 192 blocks underfills 256 CUs; FETCH unchanged ->
//    redundancy was never the HBM term.
// THIS ROUND (r8): r0 EXACTLY, except B never touches LDS: fragment-packed
// weights (r5 pack) loaded global->VGPR at the TOP of each iter, so the
// pre-compute barrier's vmcnt(0) drain (already paid for A) absorbs B's
// latency. Halves ds_reads (16->8/lane/iter) and LDS writes (32->16KB).

typedef __attribute__((ext_vector_type(8))) short   short8;
typedef __attribute__((ext_vector_type(4))) float   floatx4;
typedef unsigned short ushort_t;

__device__ inline ushort_t f2bf(float f){
  unsigned u = __float_as_uint(f);
  unsigned r = (u + 0x7FFFu + ((u >> 16) & 1u)) >> 16;   // RNE
  return (ushort_t)r;
}
__device__ inline float bf2f(ushort_t b){ return __uint_as_float(((unsigned)b) << 16); }

__device__ inline float sigm(float x){ return 1.0f / (1.0f + __expf(-x)); }
__device__ inline float tanh_fast(float x){
  float a = fabsf(x);
  float e = __expf(-2.0f * a);          // no overflow: e in (0,1]
  float r = (1.0f - e) / (1.0f + e);
  return copysignf(r, x);
}

// Column permutation (r0's verified 128-col-tile version): permuted col p ->
// original gate-major col. Tile Tt (128 cols) owns u in [Tt*32, Tt*32+32);
// within tile: two 64-col halves (one per wave_n), each half = 4 gates x 16
// u's, gate-major in 16-col groups.
__device__ inline int orig_col(int p){
  int Tt  = p >> 7;
  int loc = p & 127;
  int half = loc >> 6;
  int loc2 = loc & 63;
  int gate = loc2 >> 4;
  int uu   = (half << 4) | (loc2 & 15);
  return gate * U_ + Tt * 32 + uu;
}

#define AS1(p) ((const __attribute__((address_space(1))) void*)(p))
#define AS3(p) ((__attribute__((address_space(3))) void*)(p))

// ---------------------------------------------------------------------------
// One-time weight repack: fp32 -> bf16 in PER-WAVE FRAGMENT order (verified
// r5 pack, same 2x2-wave geometry as r0):
//   Bf[nt][w][ks32][wn][lane][8], linear idx =
//     ((((nt*2 + w)*(KL/32) + ks32)*4 + wn)*64 + lane)*8 + j
//   element = B^T[n = p][k],  p = nt*128 + w*64 + wn*16 + (lane&15),
//                             k = ks32*32 + (lane>>4)*8 + j
// so each wave's B-fragment load is one contiguous 1KB coalesced read.
// Also permuted biases (fp32) and W0 row.
// ---------------------------------------------------------------------------
__global__ void convert_weights(
    const float* __restrict__ W0, const float* __restrict__ U0, const float* __restrict__ b0,
    const float* __restrict__ W1, const float* __restrict__ U1, const float* __restrict__ b1,
    const float* __restrict__ W2, const float* __restrict__ U2, const float* __restrict__ b2,
    ushort_t* __restrict__ Bf0, ushort_t* __restrict__ Bf1, ushort_t* __restrict__ Bf2,
    float* __restrict__ W0p, float* __restrict__ biasp)
{
  const int N0 = NG_ * 512;     // Bf0 elements (KL=512)
  const int N1 = NG_ * 1024;    // Bf1/Bf2 elements (KL=1024)
  const int total = N0 + 2 * N1 + NG_ + 3 * NG_;
  int idx = blockIdx.x * 256 + threadIdx.x;
  if (idx >= total) return;

  if (idx < N0){
    // KL=512: j[2:0] l[8:3] wn[10:9] ks[14:11] w[15] nt[19:16]
    int i = idx;
    int j = i & 7, l = (i >> 3) & 63, wn = (i >> 9) & 3;
    int ks = (i >> 11) & 15, w = (i >> 15) & 1, nt = i >> 16;
    int p = nt * 128 + w * 64 + wn * 16 + (l & 15);
    int k = ks * 32 + ((l >> 4) << 3) + j;
    Bf0[i] = f2bf(U0[(size_t)k * NG_ + orig_col(p)]);
  } else if (idx < N0 + 2 * N1){
    // KL=1024: j[2:0] l[8:3] wn[10:9] ks[15:11] w[16] nt[20:17]
    int seg = (idx - N0) / N1;          // 0 -> layer1, 1 -> layer2
    int i = (idx - N0) - seg * N1;
    int j = i & 7, l = (i >> 3) & 63, wn = (i >> 9) & 3;
    int ks = (i >> 11) & 31, w = (i >> 16) & 1, nt = i >> 17;
    int p = nt * 128 + w * 64 + wn * 16 + (l & 15);
    int k = ks * 32 + ((l >> 4) << 3) + j;
    int oc = orig_col(p);
    const float* Wl = (seg == 0) ? W1 : W2;
    const float* Ul = (seg == 0) ? U1 : U2;
    float v = (k < 512) ? Wl[(size_t)k * NG_ + oc] : Ul[(size_t)(k - 512) * NG_ + oc];
    ushort_t* Bf = (seg == 0) ? Bf1 : Bf2;
    Bf[i] = f2bf(v);
  } else if (idx < N0 + 2 * N1 + NG_){
    int p = idx - N0 - 2 * N1;
    W0p[p] = W0[orig_col(p)];
  } else {
    int j = idx - N0 - 2 * N1 - NG_;
    int l = j >> 11, p = j & 2047;
    const float* bs = (l == 0) ? b0 : (l == 1) ? b1 : b2;
    biasp[j] = bs[orig_col(p)];
  }
}

// ---------------------------------------------------------------------------
// One fused GEMM (bf16 MFMA) + LSTM-cell task for a (layer, timestep),
// 128x128 tile at (mt, nt). BK=64 K-loop, r0's verified structure with B
// moved out of LDS:
//  - iter top: 8 B-frag register loads (coalesced 1KB/wave, L2/L1-resident)
//    + 4 global_load_lds for the 128x64 A tile (verified 8-slot rotation).
//  - __syncthreads (compiler drains vmcnt(0): A in LDS AND B in regs).
//  - 8 ds_read_b128 A-frags + 32 MFMA; __syncthreads.
// 256 threads = 2x2 waves, each wave 4x4 frags of 16x16x32, 2 k-steps/iter.
// ---------------------------------------------------------------------------
template<int LAYER>
__device__ __forceinline__ void do_task(
    const ushort_t* __restrict__ A0,   // phase-0 A (h_below / h_prev for L0)
    const ushort_t* __restrict__ A1,   // phase-1 A (h_prev), LAYER>0
    const ushort_t* __restrict__ Bf,   // fragment-packed weights
    const float* __restrict__ biasp,   // permuted bias for this layer (2048)
    const float* __restrict__ W0p,     // permuted W0 row (L0 only)
    const float* __restrict__ x,       // (B,T) fp32 (L0 only)
    const int* __restrict__ mask,      // (B,T) int32
    float* __restrict__ cbuf,          // (B,U) fp32, in/out
    const ushort_t* __restrict__ hprev,// this layer's previous h (mask carry)
    ushort_t* __restrict__ hout,       // (B,U) bf16 out
    int t, int mt, int nt,
    ushort_t* tA)                      // 128x64 (16 KB)
{
  constexpr int NPHASE = (LAYER == 0) ? 1 : 2;
  constexpr bool IS_L0 = (LAYER == 0);
  constexpr int K  = NPHASE * 512;
  constexpr int NK = NPHASE * 8;      // BK=64 iterations

  const int tid  = threadIdx.x;
  const int wv   = tid >> 6;
  const int lane = tid & 63;
  const int qd   = lane >> 4;     // quad 0..3
  const int l16  = lane & 15;
  const int wave_m = wv >> 1;     // 0..1
  const int wave_n = wv & 1;      // 0..1
  const int m0 = mt * 128, n0 = nt * 128;

  // A staging identity (r0): chunk i = cc*256 + tid over the 1024 16B-chunks
  // of a 128x64 tile; r = i>>3 (row), slot j = i&7 holds source chunk (j+r)&7.
  int srow[4], scol[4];
  #pragma unroll
  for (int cc = 0; cc < 4; ++cc){
    int i = cc * 256 + tid;
    srow[cc] = i >> 3;
    scol[cc] = ((i & 7) + (i >> 3)) & 7;
  }

  // A LDS read offsets (r0): frag (ks, wm): row Ra, chunk q = ks*4+qd at
  // slot (q - Ra) & 7. Loop-invariant.
  int aoff[2][4];
  #pragma unroll
  for (int ks = 0; ks < 2; ++ks){
    #pragma unroll
    for (int w = 0; w < 4; ++w){
      int Ra = wave_m * 64 + w * 16 + l16;
      int q  = ks * 4 + qd;
      aoff[ks][w] = Ra * 64 + ((q - Ra) & 7) * 8;
    }
  }

  // Per-wave fragment-packed B base: group (nt, wave_n) spans K*64 elements.
  const ushort_t* Bw = Bf + (size_t)(nt * 2 + wave_n) * ((size_t)K * 64)
                          + (size_t)lane * 8;

  floatx4 acc[4][4];
  #pragma unroll
  for (int i = 0; i < 4; ++i)
    #pragma unroll
    for (int j = 0; j < 4; ++j) acc[i][j] = (floatx4){0.f, 0.f, 0.f, 0.f};

  for (int kk = 0; kk < NK; ++kk){
    // B fragments for THIS iter, issued first: latency absorbed by the same
    // barrier drain that already waits for the A stage (r0's cost, no new
    // exposure — the r5 lesson applied correctly).
    const ushort_t* bkk = Bw + (size_t)kk * 4096;
    short8 bfr[2][4];
    #pragma unroll
    for (int ks = 0; ks < 2; ++ks)
      #pragma unroll
      for (int wn = 0; wn < 4; ++wn)
        bfr[ks][wn] = *(const short8*)&bkk[ks * 2048 + wn * 512];

    // A stage (r0 path, unchanged).
    const ushort_t* A = (NPHASE == 2 && kk >= 8) ? A1 : A0;
    const int k0 = (kk & 7) << 6;
    #pragma unroll
    for (int cc = 0; cc < 4; ++cc){
      int ibase = cc * 256 + wv * 64;   // wave-uniform; HW adds lane*16B
      const ushort_t* ga = A + (size_t)(m0 + srow[cc]) * U_ + k0 + scol[cc] * 8;
      __builtin_amdgcn_global_load_lds(AS1(ga), AS3(&tA[ibase * 8]), 16, 0, 0);
    }
    __syncthreads();

    #pragma unroll
    for (int ks = 0; ks < 2; ++ks){
      short8 af[4];
      #pragma unroll
      for (int wm = 0; wm < 4; ++wm)
        af[wm] = *(const short8*)&tA[aoff[ks][wm]];
      #pragma unroll
      for (int wm = 0; wm < 4; ++wm)
        #pragma unroll
        for (int wn = 0; wn < 4; ++wn)
          acc[wm][wn] = __builtin_amdgcn_mfma_f32_16x16x32_bf16(af[wm], bfr[ks][wn], acc[wm][wn], 0, 0, 0);
    }
    __syncthreads();
  }

  // ---- epilogue: LSTM cell, fully in-register per lane (r0 verbatim) ----
  const int u  = nt * 32 + wave_n * 16 + l16;
  const int pb = nt * 128 + wave_n * 64 + l16;
  const float bi = biasp[pb], bf_ = biasp[pb + 16], bg = biasp[pb + 32], bo = biasp[pb + 48];
  float wi = 0.f, wf = 0.f, wg = 0.f, wo = 0.f;
  if (IS_L0){ wi = W0p[pb]; wf = W0p[pb + 16]; wg = W0p[pb + 32]; wo = W0p[pb + 48]; }

  #pragma unroll
  for (int wm = 0; wm < 4; ++wm){
    #pragma unroll
    for (int reg = 0; reg < 4; ++reg){
      int b = m0 + wave_m * 64 + wm * 16 + qd * 4 + reg;
      float zi = acc[wm][0][reg] + bi;
      float zf = acc[wm][1][reg] + bf_;
      float zg = acc[wm][2][reg] + bg;
      float zo = acc[wm][3][reg] + bo;
      if (IS_L0){
        float xv = x[(size_t)b * T_ + t];
        zi += xv * wi; zf += xv * wf; zg += xv * wg; zo += xv * wo;
      }
      int mk = mask[(size_t)b * T_ + t];
      size_t su = (size_t)b * U_ + u;
      float c_old = cbuf[su];
      float i_ = sigm(zi), f_ = sigm(zf), g_ = tanh_fast(zg), o_ = sigm(zo);
      float c_new = f_ * c_old + i_ * g_;
      float h_new = o_ * tanh_fast(c_new);
      ushort_t hb = mk ? f2bf(h_new) : hprev[su];
      cbuf[su] = mk ? c_new : c_old;
      hout[su] = hb;
    }
  }
}

// ---------------------------------------------------------------------------
// One wavefront phase: L0(t=s), L1(t=s-1), L2(t=s-2) are independent ->
// 768 blocks (3 tasks x 256 tiles) = 3 blocks/CU (16KB LDS each). Blocks
// {lin, lin+256, lin+512} (same tile, tasks 0/1/2) land on the same CU under
// round-robin dispatch -> per-CU load uniform (8+16+16 K-iters) and the
// three tasks share mask/x cachelines in L1.
// ---------------------------------------------------------------------------
__global__ __launch_bounds__(256, 3) void lstm_phase(
    const ushort_t* __restrict__ Bf0, const ushort_t* __restrict__ Bf1,
    const ushort_t* __restrict__ Bf2, const float* __restrict__ biasp,
    const float* __restrict__ W0p, const float* __restrict__ x,
    const int* __restrict__ mask,
    ushort_t* h00, ushort_t* h01, ushort_t* h10, ushort_t* h11,
    ushort_t* h20, ushort_t* h21,
    float* c0, float* c1, float* c2,
    int s)
{
  __shared__ __align__(16) ushort_t tA[128 * 64];   // 16 KB (A only)

  const int lin  = blockIdx.x;
  const int task = lin >> 8;        // 0..2
  const int tile = lin & 255;       // 0..255
  const int mt = tile >> 4, nt = tile & 15;

  ushort_t* h0[2] = {h00, h01};
  ushort_t* h1[2] = {h10, h11};
  ushort_t* h2[2] = {h20, h21};

  if (task == 0){
    if (s >= 100) return;
    int t = s, p = t & 1;
    do_task<0>(h0[p], nullptr, Bf0, biasp, W0p, x, mask,
               c0, h0[p], h0[p ^ 1], t, mt, nt, tA);
  } else if (task == 1){
    if (s < 1 || s > 100) return;
    int t = s - 1, p = t & 1;
    do_task<1>(h0[p ^ 1], h1[p], Bf1, biasp + NG_, nullptr, x, mask,
               c1, h1[p], h1[p ^ 1], t, mt, nt, tA);
  } else {
    if (s < 2) return;
    int t = s - 2, p = t & 1;
    do_task<2>(h1[p ^ 1], h2[p], Bf2, biasp + 2 * NG_, nullptr, x, mask,
               c2, h2[p], h2[p ^ 1], t, mt, nt, tA);
  }
}

// ---------------------------------------------------------------------------
// Head: logits = h2 @ Wd + bd, softmax. One wave per batch row.
// ---------------------------------------------------------------------------
__global__ __launch_bounds__(256) void head_softmax(
    const ushort_t* __restrict__ h2, const float* __restrict__ Wd,
    const float* __restrict__ bd, float* __restrict__ out)
{
  int wv = threadIdx.x >> 6, lane = threadIdx.x & 63;
  int row = blockIdx.x * 4 + wv;
  const ushort_t* hr = h2 + (size_t)row * U_;

  float acc[C_];
  #pragma unroll
  for (int c = 0; c < C_; ++c) acc[c] = 0.f;

  short8 hv = *(const short8*)&hr[lane * 8];
  #pragma unroll
  for (int j = 0; j < 8; ++j){
    float hf = bf2f((ushort_t)hv[j]);
    int k = lane * 8 + j;
    #pragma unroll
    for (int c = 0; c < C_; ++c) acc[c] += hf * Wd[k * C_ + c];
  }
  #pragma unroll
  for (int c = 0; c < C_; ++c){
    float v = acc[c];
    #pragma unroll
    for (int off = 32; off > 0; off >>= 1) v += __shfl_xor(v, off);
    acc[c] = v + bd[c];
  }
  float mx = acc[0];
  #pragma unroll
  for (int c = 1; c < C_; ++c) mx = fmaxf(mx, acc[c]);
  float e[C_]; float s = 0.f;
  #pragma unroll
  for (int c = 0; c < C_; ++c){ e[c] = __expf(acc[c] - mx); s += e[c]; }
  float inv = 1.0f / s;
  if (lane == 0){
    #pragma unroll
    for (int c = 0; c < C_; ++c) out[(size_t)row * C_ + c] = e[c] * inv;
  }
}

// ---------------------------------------------------------------------------
extern "C" void kernel_launch(void* const* d_in, const int* in_sizes, int n_in,
                              void* d_out, int out_size, void* d_ws, size_t ws_size,
                              hipStream_t stream)
{
  const float* x  = (const float*)d_in[0];
  const int*  mask= (const int*)  d_in[1];
  const float* W0 = (const float*)d_in[2];
  const float* U0 = (const float*)d_in[3];
  const float* b0 = (const float*)d_in[4];
  const float* W1 = (const float*)d_in[5];
  const float* U1 = (const float*)d_in[6];
  const float* b1 = (const float*)d_in[7];
  const float* W2 = (const float*)d_in[8];
  const float* U2 = (const float*)d_in[9];
  const float* b2 = (const float*)d_in[10];
  const float* Wd = (const float*)d_in[11];
  const float* bd = (const float*)d_in[12];
  float* out = (float*)d_out;

  char* ws = (char*)d_ws;
  size_t off = 0;
  auto alloc = [&](size_t sz) -> char* {
    char* p = ws + off; off = (off + sz + 255) & ~(size_t)255; return p;
  };
  ushort_t* Bf0  = (ushort_t*)alloc((size_t)NG_ * 512 * 2);
  ushort_t* Bf1  = (ushort_t*)alloc((size_t)NG_ * 1024 * 2);
  ushort_t* Bf2  = (ushort_t*)alloc((size_t)NG_ * 1024 * 2);
  float*    W0p  = (float*)alloc((size_t)NG_ * 4);
  float*    biasp= (float*)alloc((size_t)3 * NG_ * 4);

  // State: h[3][2] (bf16) + c[3] (fp32), one contiguous memset region.
  const size_t hsz = (size_t)B_ * U_ * 2;
  const size_t csz = (size_t)B_ * U_ * 4;
  char* state = alloc(6 * hsz + 3 * csz);
  ushort_t* hb[3][2]; float* cb[3];
  {
    char* pp = state;
    for (int l = 0; l < 3; ++l)
      for (int par = 0; par < 2; ++par){ hb[l][par] = (ushort_t*)pp; pp += hsz; }
    for (int l = 0; l < 3; ++l){ cb[l] = (float*)pp; pp += csz; }
  }

  hipMemsetAsync(state, 0, 6 * hsz + 3 * csz, stream);

  const int total = NG_ * 512 + 2 * NG_ * 1024 + NG_ + 3 * NG_;
  convert_weights<<<(total + 255) / 256, 256, 0, stream>>>(
      W0, U0, b0, W1, U1, b1, W2, U2, b2, Bf0, Bf1, Bf2, W0p, biasp);

  for (int s = 0; s < 102; ++s){
    lstm_phase<<<768, 256, 0, stream>>>(
        Bf0, Bf1, Bf2, biasp, W0p, x, mask,
        hb[0][0], hb[0][1], hb[1][0], hb[1][1], hb[2][0], hb[2][1],
        cb[0], cb[1], cb[2], s);
  }

  // T=100: layer-2 final h (t=99) lands in parity-0 buffer.
  head_softmax<<<B_ / 4, 256, 0, stream>>>(hb[2][0], Wd, bd, out);
}